// Round 10
// baseline (1127.488 us; speedup 1.0000x reference)
//
#include <hip/hip_runtime.h>
#include <cstdint>
#include <cstddef>

// Problem constants
#define BB   4
#define TT   1024
#define CC   1024
#define HH   16
#define HSS  64
#define NNtok 4096            // B*T
#define EPSGN 0.00064f

typedef unsigned short bf16u;
typedef __attribute__((ext_vector_type(8))) short short8;
typedef __attribute__((ext_vector_type(4))) float f32x4;
#define SLOT 4194304ull       // elements per 8MiB bf16 slot (= NNtok*CC)

__device__ __forceinline__ float bf2f(bf16u u){
  union { unsigned int i; float f; } cv; cv.i = ((unsigned int)u) << 16; return cv.f;
}
__device__ __forceinline__ unsigned short f2bfbits(unsigned int x){
  return (unsigned short)((x + 0x7fffu + ((x >> 16) & 1u)) >> 16);   // RNE
}
__device__ __forceinline__ bf16u f2bf(float f){
  union { float f; unsigned int i; } cv; cv.f = f;
  return f2bfbits(cv.i);
}
__device__ __forceinline__ void ld4bf(const bf16u* p, float* o){
  ushort4 u = *reinterpret_cast<const ushort4*>(p);
  o[0]=bf2f(u.x); o[1]=bf2f(u.y); o[2]=bf2f(u.z); o[3]=bf2f(u.w);
}
__device__ __forceinline__ void st4bf(bf16u* p, const float* v){
  ushort4 u; u.x=f2bf(v[0]); u.y=f2bf(v[1]); u.z=f2bf(v[2]); u.w=f2bf(v[3]);
  *reinterpret_cast<ushort4*>(p) = u;
}
__device__ __forceinline__ void ld4f(const float* p, float* o){
  float4 v = *reinterpret_cast<const float4*>(p);
  o[0]=v.x; o[1]=v.y; o[2]=v.z; o[3]=v.w;
}
__device__ __forceinline__ float sigm(float x){ return 1.f / (1.f + expf(-x)); }

// 16-lane sum via DPP (groups must be 16-lane aligned).
template<int CTRL>
__device__ __forceinline__ float dpp_add(float v){
  union { float f; int i; } a, b;
  a.f = v;
  b.i = __builtin_amdgcn_update_dpp(a.i, a.i, CTRL, 0xF, 0xF, false);
  return v + b.f;
}
__device__ __forceinline__ float red16(float v){
  v = dpp_add<0xB1>(v);    // quad_perm [1,0,3,2]  (xor 1)
  v = dpp_add<0x4E>(v);    // quad_perm [2,3,0,1]  (xor 2)
  v = dpp_add<0x124>(v);   // row_ror:4
  v = dpp_add<0x128>(v);   // row_ror:8
  return v;
}

// ---------------------------------------------------------------------------
// mix = x + (x[t-1]-x[t])*time_maa_x  (x[-1]=0), stored bf16
// ---------------------------------------------------------------------------
__global__ __launch_bounds__(256) void k_prep(const float* __restrict__ x,
                                              const float* __restrict__ tmx,
                                              bf16u* __restrict__ MIX){
  int e = (blockIdx.x * 256 + threadIdx.x) * 4;
  int n = e >> 10;
  int c = e & (CC - 1);
  int t = n & (TT - 1);
  float xf[4]; ld4f(x + e, xf);
  float pf[4] = {0.f, 0.f, 0.f, 0.f};
  if (t > 0) ld4f(x + e - CC, pf);
  float tm[4]; ld4f(tmx + c, tm);
  float mv[4];
  #pragma unroll
  for (int i = 0; i < 4; ++i) mv[i] = xf[i] + (pf[i] - xf[i]) * tm[i];
  st4bf(MIX + e, mv);
}

// ---------------------------------------------------------------------------
// MFMA NT GEMM, software-pipelined staging (prefetch next K-tile into regs
// during MFMA section). W as up to 3 f32 row-blocks. tanh on cols < act_n.
// OB: bf16 out. POFF >= 0: packed output  idx = row*4096 + (col>>6)*256 +
// POFF + (col&63)  (head-interleaved KPACK layout).
// ---------------------------------------------------------------------------
template<bool OB, int POFF>
__global__ __launch_bounds__(256) void k_gemm_mfma(const bf16u* __restrict__ X,
                                                   const float* __restrict__ Wa,
                                                   const float* __restrict__ Wb,
                                                   const float* __restrict__ Wc,
                                                   int na, int nab,
                                                   void* __restrict__ OUTv,
                                                   int Nd, int Kd, int act_n){
  __shared__ short As[128 * 40];
  __shared__ short Bs[128 * 40];
  const int tid  = threadIdx.x;
  const int lane = tid & 63;
  const int wv   = tid >> 6;
  const int wm   = wv >> 1, wn = wv & 1;
  const int bn0  = blockIdx.x * 128;
  const int bm0  = blockIdx.y * 128;
  const int l15  = lane & 15;
  const int quad = lane >> 4;

  f32x4 acc[4][4];
  #pragma unroll
  for (int mi = 0; mi < 4; ++mi)
    #pragma unroll
    for (int ni = 0; ni < 4; ++ni)
      #pragma unroll
      for (int rg = 0; rg < 4; ++rg) acc[mi][ni][rg] = 0.f;

  const int r    = tid >> 1;
  const int half = (tid & 1) * 16;

  int rr = bn0 + r;
  const float* wsrc = nullptr;
  if (rr < na)        wsrc = Wa + (size_t)rr * Kd;
  else if (rr < nab)  wsrc = Wb + (size_t)(rr - na) * Kd;
  else if (rr < Nd)   wsrc = Wc + (size_t)(rr - nab) * Kd;
  const bf16u* xsrc = X + (size_t)(bm0 + r) * Kd;

  // prefetch registers (tile k0 = 0)
  uint4 xa = *(const uint4*)(xsrc + half);
  uint4 xb = *(const uint4*)(xsrc + half + 8);
  uint4 w0 = make_uint4(0,0,0,0), w1 = w0, w2 = w0, w3 = w0;
  if (wsrc){
    w0 = *(const uint4*)(wsrc + half);
    w1 = *(const uint4*)(wsrc + half + 4);
    w2 = *(const uint4*)(wsrc + half + 8);
    w3 = *(const uint4*)(wsrc + half + 12);
  }

  for (int k0 = 0; k0 < Kd; k0 += 32){
    union { unsigned short s[8]; uint4 v; } p0, p1;
    p0.s[0]=f2bfbits(w0.x); p0.s[1]=f2bfbits(w0.y); p0.s[2]=f2bfbits(w0.z); p0.s[3]=f2bfbits(w0.w);
    p0.s[4]=f2bfbits(w1.x); p0.s[5]=f2bfbits(w1.y); p0.s[6]=f2bfbits(w1.z); p0.s[7]=f2bfbits(w1.w);
    p1.s[0]=f2bfbits(w2.x); p1.s[1]=f2bfbits(w2.y); p1.s[2]=f2bfbits(w2.z); p1.s[3]=f2bfbits(w2.w);
    p1.s[4]=f2bfbits(w3.x); p1.s[5]=f2bfbits(w3.y); p1.s[6]=f2bfbits(w3.z); p1.s[7]=f2bfbits(w3.w);

    __syncthreads();                 // prev tile's readers done
    *(uint4*)&As[r * 40 + half]     = xa;
    *(uint4*)&As[r * 40 + half + 8] = xb;
    *(uint4*)&Bs[r * 40 + half]     = p0.v;
    *(uint4*)&Bs[r * 40 + half + 8] = p1.v;
    __syncthreads();

    if (k0 + 32 < Kd){               // issue next-tile loads; overlap w/ MFMA
      xa = *(const uint4*)(xsrc + k0 + 32 + half);
      xb = *(const uint4*)(xsrc + k0 + 32 + half + 8);
      if (wsrc){
        w0 = *(const uint4*)(wsrc + k0 + 32 + half);
        w1 = *(const uint4*)(wsrc + k0 + 32 + half + 4);
        w2 = *(const uint4*)(wsrc + k0 + 32 + half + 8);
        w3 = *(const uint4*)(wsrc + k0 + 32 + half + 12);
      }
    }

    short8 af[4], bfg[4];
    #pragma unroll
    for (int mi = 0; mi < 4; ++mi)
      af[mi] = *(const short8*)&As[(wm*64 + mi*16 + l15) * 40 + quad*8];
    #pragma unroll
    for (int ni = 0; ni < 4; ++ni)
      bfg[ni] = *(const short8*)&Bs[(wn*64 + ni*16 + l15) * 40 + quad*8];
    #pragma unroll
    for (int mi = 0; mi < 4; ++mi)
      #pragma unroll
      for (int ni = 0; ni < 4; ++ni)
        acc[mi][ni] = __builtin_amdgcn_mfma_f32_16x16x32_bf16(af[mi], bfg[ni], acc[mi][ni], 0, 0, 0);
  }

  #pragma unroll
  for (int mi = 0; mi < 4; ++mi){
    #pragma unroll
    for (int ni = 0; ni < 4; ++ni){
      int col = bn0 + wn*64 + ni*16 + l15;
      if (col >= Nd) continue;
      #pragma unroll
      for (int rg = 0; rg < 4; ++rg){
        int row = bm0 + wm*64 + mi*16 + quad*4 + rg;
        float v = acc[mi][ni][rg];
        if (col < act_n) v = tanhf(v);
        if (POFF >= 0)
          ((bf16u*)OUTv)[(size_t)row * 4096 + ((col >> 6) << 8) + POFF + (col & 63)] = f2bf(v);
        else if (OB)
          ((bf16u*)OUTv)[(size_t)row * Nd + col] = f2bf(v);
        else
          ((float*)OUTv)[(size_t)row * Nd + col] = v;
      }
    }
  }
}

// ---------------------------------------------------------------------------
// MFMA NN GEMM: OUT[M, CC] = A[M, KD](bf16, stride lda) @ B[KD, CC](f32).
// EP=1: token-shift epilogue. POFF>=0: packed output (KPACK position).
// ---------------------------------------------------------------------------
template<int KD, int EP, int POFF>
__global__ __launch_bounds__(256) void k_gemm_nn(const bf16u* __restrict__ A, int lda,
                                                 const float* __restrict__ B,
                                                 bf16u* __restrict__ OUT,
                                                 const float* __restrict__ x,
                                                 const float* __restrict__ tma_g){
  __shared__ short As[128 * (KD + 8)];
  __shared__ short Bs[128 * (KD + 8)];
  const int tid  = threadIdx.x;
  const int lane = tid & 63;
  const int wv   = tid >> 6;
  const int wm   = wv >> 1, wn = wv & 1;
  const int bn0  = blockIdx.x * 128;
  const int bm0  = blockIdx.y * 128;
  const int l15  = lane & 15;
  const int quad = lane >> 4;

  for (int idx = tid; idx < 128 * (KD / 8); idx += 256){
    int r  = idx / (KD / 8);
    int kc = (idx % (KD / 8)) * 8;
    *(uint4*)&As[r * (KD + 8) + kc] =
        *(const uint4*)(A + (size_t)(bm0 + r) * lda + kc);
  }
  for (int idx = tid; idx < KD * 128; idx += 256){
    int k = idx >> 7, c = idx & 127;
    Bs[c * (KD + 8) + k] = (short)f2bf(B[(size_t)k * CC + bn0 + c]);
  }
  __syncthreads();

  f32x4 acc[4][4];
  #pragma unroll
  for (int mi = 0; mi < 4; ++mi)
    #pragma unroll
    for (int ni = 0; ni < 4; ++ni)
      #pragma unroll
      for (int rg = 0; rg < 4; ++rg) acc[mi][ni][rg] = 0.f;

  #pragma unroll
  for (int kk = 0; kk < KD; kk += 32){
    short8 af[4], bfg[4];
    #pragma unroll
    for (int mi = 0; mi < 4; ++mi)
      af[mi] = *(const short8*)&As[(wm*64 + mi*16 + l15) * (KD + 8) + kk + quad*8];
    #pragma unroll
    for (int ni = 0; ni < 4; ++ni)
      bfg[ni] = *(const short8*)&Bs[(wn*64 + ni*16 + l15) * (KD + 8) + kk + quad*8];
    #pragma unroll
    for (int mi = 0; mi < 4; ++mi)
      #pragma unroll
      for (int ni = 0; ni < 4; ++ni)
        acc[mi][ni] = __builtin_amdgcn_mfma_f32_16x16x32_bf16(af[mi], bfg[ni], acc[mi][ni], 0, 0, 0);
  }

  #pragma unroll
  for (int mi = 0; mi < 4; ++mi){
    #pragma unroll
    for (int ni = 0; ni < 4; ++ni){
      int col = bn0 + wn*64 + ni*16 + l15;
      float tm = (EP == 1) ? tma_g[col] : 0.f;
      #pragma unroll
      for (int rg = 0; rg < 4; ++rg){
        int row = bm0 + wm*64 + mi*16 + quad*4 + rg;
        float v = acc[mi][ni][rg];
        if (EP == 1){
          float xv = x[(size_t)row * CC + col];
          float xp = ((row & (TT - 1)) == 0) ? 0.f : x[(size_t)row * CC + col - CC];
          v = xv + (xp - xv) * (v + tm);
        }
        if (POFF >= 0)
          OUT[(size_t)row * 4096 + ((col >> 6) << 8) + POFF + (col & 63)] = f2bf(v);
        else
          OUT[(size_t)row * CC + col] = f2bf(v);
      }
    }
  }
}

// ---------------------------------------------------------------------------
// Fused elementwise on KPACK (in-place), tiled 4 tokens/block.
// KPACK per (n,h): [kkn|b|kf|u] x 64.  On entry kf-pos holds raw k0 (Wk out),
// u-pos holds raw w2a (decay-LoRA out).
// ---------------------------------------------------------------------------
__global__ __launch_bounds__(256) void k_elem(bf16u* __restrict__ KP,
    const bf16u* __restrict__ P1, const bf16u* __restrict__ P2,
    const float* __restrict__ kw2, const float* __restrict__ aw2,
    const float* __restrict__ maw2, const float* __restrict__ mkw2,
    const float* __restrict__ td,  const float* __restrict__ taa,
    const float* __restrict__ tma, const float* __restrict__ tmk){
  int n0 = blockIdx.x * 4, tid = threadIdx.x;
  __shared__ float at_l[4][16], mat_l[4][16], kt_l[4][16], mkt_l[4][16];
  {
    int grp = tid >> 6, q = tid & 63, tt = q >> 4, j = q & 15;
    if (grp == 0)      at_l[tt][j]  = bf2f(P1[(size_t)(n0+tt)*96 + 64 + j]);
    else if (grp == 1) mat_l[tt][j] = bf2f(P1[(size_t)(n0+tt)*96 + 80 + j]);
    else if (grp == 2) kt_l[tt][j]  = bf2f(P2[(size_t)(n0+tt)*32 + j]);
    else               mkt_l[tt][j] = bf2f(P2[(size_t)(n0+tt)*32 + 16 + j]);
  }
  __syncthreads();
  int c = tid * 4;
  int h = c >> 6, jj = c & 63;

  float kkk[4][4], aa[4][4], mam[4][4], mkm[4][4];
  #pragma unroll
  for (int tt = 0; tt < 4; ++tt)
    #pragma unroll
    for (int i = 0; i < 4; ++i){ kkk[tt][i]=0; aa[tt][i]=0; mam[tt][i]=0; mkm[tt][i]=0; }

  #pragma unroll 4
  for (int j = 0; j < 16; ++j){
    float wk[4], wa[4], wm[4], wq[4];
    ld4f(kw2  + (size_t)j*CC + c, wk);
    ld4f(aw2  + (size_t)j*CC + c, wa);
    ld4f(maw2 + (size_t)j*CC + c, wm);
    ld4f(mkw2 + (size_t)j*CC + c, wq);
    #pragma unroll
    for (int tt = 0; tt < 4; ++tt){
      float s1 = kt_l[tt][j], s2 = at_l[tt][j], s3 = mat_l[tt][j], s4 = mkt_l[tt][j];
      #pragma unroll
      for (int i = 0; i < 4; ++i){
        kkk[tt][i] += s1 * wk[i];
        aa[tt][i]  += s2 * wa[i];
        mam[tt][i] += s3 * wm[i];
        mkm[tt][i] += s4 * wq[i];
      }
    }
  }

  float td4[4], taa4[4], tma4[4], tmk4[4];
  ld4f(td + c, td4); ld4f(taa + c, taa4); ld4f(tma + c, tma4); ld4f(tmk + c, tmk4);

  for (int tt = 0; tt < 4; ++tt){
    size_t base = (size_t)(n0 + tt) * 4096 + h * 256 + jj;
    float k0a[4]; ld4bf(KP + base + 128, k0a);   // raw k0
    float w2a[4]; ld4bf(KP + base + 192, w2a);   // raw decay lora

    float kkv[4];
    float ssq = 0.f;
    #pragma unroll
    for (int i = 0; i < 4; ++i){ kkv[i] = k0a[i] + kkk[tt][i]; ssq += kkv[i]*kkv[i]; }
    ssq = red16(ssq);
    float rinv = 1.f / fmaxf(sqrtf(ssq), 1e-12f);

    float kkn[4], outb[4], outkf[4], outu[4];
    #pragma unroll
    for (int i = 0; i < 4; ++i){
      float z  = td4[i] + w2a[i];
      float nz = -z;
      float sp = (nz > 15.f) ? nz : log1pf(expf(nz));
      float w  = -sp - 0.5f;               // <= -0.5
      float av  = sigm(taa4[i] + aa[tt][i]);
      float mav = sigm(tma4[i] + mam[tt][i]);
      float mkv = sigm(tmk4[i] + mkm[tt][i]);
      kkn[i]  = kkv[i] * rinv;
      outb[i] = -kkn[i] * av;
      outkf[i]= k0a[i] * (mav + av * (1.f - mav)) * expf(w * mkv);
      outu[i] = expf(w);                   // in (0, 0.61]
    }
    st4bf(KP + base,       kkn);
    st4bf(KP + base + 64,  outb);
    st4bf(KP + base + 128, outkf);
    st4bf(KP + base + 192, outu);
  }
}

// ---------------------------------------------------------------------------
// Recurrence v6: row-parallel, DPP reductions, KPACK single-base loads,
// transposed YT output with one 8B store per 4 steps.
// ---------------------------------------------------------------------------
__global__ __launch_bounds__(256) void k_rec(const bf16u* __restrict__ R,
                                             const bf16u* __restrict__ KP,
                                             const bf16u* __restrict__ Vt,
                                             bf16u* __restrict__ YT){
  const int blk = blockIdx.x;          // 0..255
  const int b   = blk >> 6;
  const int h   = (blk >> 2) & 15;
  const int rg  = blk & 3;
  const int tid = threadIdx.x;
  const int cg  = tid & 15;
  const int i   = rg * 16 + (tid >> 4);
  const int j0  = cg * 4;
  const int bh  = b * 16 + h;

  const bf16u* qp = R  + (size_t)(b * TT) * CC + h * HSS + j0;   // += CC per t
  const bf16u* kp = KP + (size_t)(b * TT) * 4096 + h * 256 + j0; // += 4096 per t
  const bf16u* vp = Vt + (size_t)(b * TT) * CC + h * HSS + i;    // += CC per t
  bf16u* yout     = YT + (size_t)(bh * 64 + i) * TT;

  float S0 = 0.f, S1 = 0.f, S2 = 0.f, S3 = 0.f;
  float ypA, ypB, ypC, ypD;

  ushort4 qA, kA, aA, bA, uA; unsigned short vA;
  ushort4 qB, kB, aB, bB, uB; unsigned short vB;
  ushort4 qC, kC, aC, bC, uC; unsigned short vC;
  ushort4 qD, kD, aD, bD, uD; unsigned short vD;

#define KREC_LOAD(SFX, T_) do{ \
    const bf16u* kb_ = kp + (size_t)(T_) * 4096; \
    a##SFX = *(const ushort4*)(kb_); \
    b##SFX = *(const ushort4*)(kb_ + 64); \
    k##SFX = *(const ushort4*)(kb_ + 128); \
    u##SFX = *(const ushort4*)(kb_ + 192); \
    q##SFX = *(const ushort4*)(qp + (size_t)(T_) * CC); \
    v##SFX = vp[(size_t)(T_) * CC]; \
  }while(0)

#define KREC_STEP(SFX) do{ \
    float a0 = bf2f(a##SFX.x), a1 = bf2f(a##SFX.y), a2 = bf2f(a##SFX.z), a3 = bf2f(a##SFX.w); \
    float w0 = __expf(-bf2f(u##SFX.x)), w1 = __expf(-bf2f(u##SFX.y)); \
    float w2 = __expf(-bf2f(u##SFX.z)), w3 = __expf(-bf2f(u##SFX.w)); \
    float k0 = bf2f(k##SFX.x), k1 = bf2f(k##SFX.y), k2 = bf2f(k##SFX.z), k3 = bf2f(k##SFX.w); \
    float b0 = bf2f(b##SFX.x), b1 = bf2f(b##SFX.y), b2 = bf2f(b##SFX.z), b3 = bf2f(b##SFX.w); \
    float q0 = bf2f(q##SFX.x), q1 = bf2f(q##SFX.y), q2 = bf2f(q##SFX.z), q3 = bf2f(q##SFX.w); \
    float vi = bf2f(v##SFX); \
    float sa = (S0 * a0 + S1 * a1) + (S2 * a2 + S3 * a3); \
    sa = red16(sa); \
    S0 = fmaf(S0, w0, fmaf(sa, b0, vi * k0)); \
    S1 = fmaf(S1, w1, fmaf(sa, b1, vi * k1)); \
    S2 = fmaf(S2, w2, fmaf(sa, b2, vi * k2)); \
    S3 = fmaf(S3, w3, fmaf(sa, b3, vi * k3)); \
    yp##SFX = (S0 * q0 + S1 * q1) + (S2 * q2 + S3 * q3); \
  }while(0)

  KREC_LOAD(A, 0); KREC_LOAD(B, 1); KREC_LOAD(C, 2); KREC_LOAD(D, 3);
  for (int t = 0; t < TT; t += 4){
    KREC_STEP(A); if (t + 4 < TT) KREC_LOAD(A, t + 4);
    KREC_STEP(B); if (t + 5 < TT) KREC_LOAD(B, t + 5);
    KREC_STEP(C); if (t + 6 < TT) KREC_LOAD(C, t + 6);
    KREC_STEP(D); if (t + 7 < TT) KREC_LOAD(D, t + 7);
    float r0 = red16(ypA), r1 = red16(ypB), r2 = red16(ypC), r3 = red16(ypD);
    if (cg == 0){
      ushort4 o; o.x = f2bf(r0); o.y = f2bf(r1); o.z = f2bf(r2); o.w = f2bf(r3);
      *(ushort4*)(yout + t) = o;
    }
  }
#undef KREC_LOAD
#undef KREC_STEP
}

// ---------------------------------------------------------------------------
// Post: GroupNorm + bonus + gate (rank-128, 4-token weight reuse).
// Reads YT (transposed), writes YG in-place over R.
// ---------------------------------------------------------------------------
__global__ __launch_bounds__(256) void k_post(const bf16u* __restrict__ YT,
                                              bf16u* __restrict__ R,   // in: r, out: yg
                                              const bf16u* __restrict__ KP,
                                              const bf16u* __restrict__ Vt,
                                              const bf16u* __restrict__ GT,
                                              const float* __restrict__ gw2,
                                              const float* __restrict__ lnw,
                                              const float* __restrict__ lnb,
                                              const float* __restrict__ faaaa){
  int n0 = blockIdx.x * 4, tid = threadIdx.x;
  __shared__ float gt_l[4][128];
  {
    int v0 = tid;        gt_l[v0 >> 7][v0 & 127] = bf2f(GT[(size_t)(n0 + (v0 >> 7)) * 128 + (v0 & 127)]);
    int v1 = tid + 256;  gt_l[v1 >> 7][v1 & 127] = bf2f(GT[(size_t)(n0 + (v1 >> 7)) * 128 + (v1 & 127)]);
  }
  __syncthreads();
  int c = tid * 4;
  int h = c >> 6, i0 = c & 63;

  float lw4[4], lb4[4], fa4[4];
  ld4f(lnw + c, lw4); ld4f(lnb + c, lb4); ld4f(faaaa + c, fa4);

  float yn[4][4];
  for (int tt = 0; tt < 4; ++tt){
    int n = n0 + tt;
    int bb = n >> 10, t = n & (TT - 1);
    size_t e = (size_t)n * CC + c;
    const bf16u* yb = YT + (size_t)((bb * 16 + h) * 64 + i0) * TT + t;
    float ya[4];
    ya[0] = bf2f(yb[0]); ya[1] = bf2f(yb[TT]); ya[2] = bf2f(yb[2*TT]); ya[3] = bf2f(yb[3*TT]);

    float s = ya[0] + ya[1] + ya[2] + ya[3];
    s = red16(s);
    float mu = s * (1.f / 64.f);
    float d[4], vs = 0.f;
    #pragma unroll
    for (int i = 0; i < 4; ++i){ d[i] = ya[i] - mu; vs += d[i] * d[i]; }
    vs = red16(vs);
    float rstd = rsqrtf(vs * (1.f / 64.f) + EPSGN);

    float r4[4], k4[4], va[4];
    ld4bf(R + e, r4);
    ld4bf(KP + (size_t)n * 4096 + h * 256 + 128 + i0, k4);
    ld4bf(Vt + e, va);
    float rk = r4[0]*k4[0]*fa4[0] + r4[1]*k4[1]*fa4[1] + r4[2]*k4[2]*fa4[2] + r4[3]*k4[3]*fa4[3];
    rk = red16(rk);

    #pragma unroll
    for (int i = 0; i < 4; ++i)
      yn[tt][i] = d[i] * rstd * lw4[i] + lb4[i] + rk * va[i];
  }

  float g[4][4];
  #pragma unroll
  for (int tt = 0; tt < 4; ++tt)
    #pragma unroll
    for (int i = 0; i < 4; ++i) g[tt][i] = 0.f;
  #pragma unroll 4
  for (int j = 0; j < 128; ++j){
    float wvv[4]; ld4f(gw2 + (size_t)j * CC + c, wvv);
    #pragma unroll
    for (int tt = 0; tt < 4; ++tt){
      float gl = gt_l[tt][j];
      #pragma unroll
      for (int i = 0; i < 4; ++i) g[tt][i] += gl * wvv[i];
    }
  }

  for (int tt = 0; tt < 4; ++tt){
    size_t e = (size_t)(n0 + tt) * CC + c;
    float o[4];
    #pragma unroll
    for (int i = 0; i < 4; ++i) o[i] = yn[tt][i] * g[tt][i];
    st4bf(R + e, o);   // in-place: same elements this thread read
  }
}

// ---------------------------------------------------------------------------
extern "C" void kernel_launch(void* const* d_in, const int* in_sizes, int n_in,
                              void* d_out, int out_size, void* d_ws, size_t ws_size,
                              hipStream_t stream){
  (void)in_sizes; (void)n_in; (void)out_size; (void)ws_size;
  const float* x        = (const float*)d_in[0];
  const float* tmx      = (const float*)d_in[1];
  const float* tmaa     = (const float*)d_in[2];
  const float* maa_w1   = (const float*)d_in[3];
  const float* maa_w2   = (const float*)d_in[4];
  const float* decay_w1 = (const float*)d_in[5];
  const float* decay_w2 = (const float*)d_in[6];
  const float* aaa_w1   = (const float*)d_in[7];
  const float* aaa_w2   = (const float*)d_in[8];
  const float* kkk_w1   = (const float*)d_in[9];
  const float* kkk_w2   = (const float*)d_in[10];
  const float* gate_w1  = (const float*)d_in[11];
  const float* gate_w2  = (const float*)d_in[12];
  const float* ma_w1    = (const float*)d_in[13];
  const float* ma_w2    = (const float*)d_in[14];
  const float* mk_w1    = (const float*)d_in[15];
  const float* mk_w2    = (const float*)d_in[16];
  const float* t_decay  = (const float*)d_in[17];
  const float* t_faaaa  = (const float*)d_in[18];
  const float* t_aaaaa  = (const float*)d_in[19];
  const float* t_misc_a = (const float*)d_in[20];
  const float* t_misc_k = (const float*)d_in[21];
  const float* Wr       = (const float*)d_in[22];
  const float* Wk       = (const float*)d_in[23];
  const float* Wv       = (const float*)d_in[24];
  const float* Wo       = (const float*)d_in[25];
  const float* ln_w     = (const float*)d_in[26];
  const float* ln_b     = (const float*)d_in[27];

  // Slots (8MiB bf16): KPACK = S0..S3 (32MiB, [n][h][kkn|b|kf|u]x64).
  // S4: MIX -> X2 -> R -> YG(in-place) | S5: X0 -> YT | S6: X1 -> V
  // X3 transiently in S0 (dies before KPACK writes begin).
  bf16u* bw  = (bf16u*)d_ws;
  bf16u* KP  = bw + 0*SLOT;   // spans S0..S3
  bf16u* X3  = bw + 0*SLOT;   // transient
  bf16u* MIX = bw + 4*SLOT;
  bf16u* X2  = bw + 4*SLOT;
  bf16u* R   = bw + 4*SLOT;
  bf16u* X0  = bw + 5*SLOT;
  bf16u* YT  = bw + 5*SLOT;
  bf16u* X1  = bw + 6*SLOT;
  bf16u* V   = bw + 6*SLOT;
  char*  wsb = (char*)d_ws;
  bf16u* LO  = (bf16u*)(wsb + (56ull<<20));   // [N,128] bf16
  bf16u* GT  = (bf16u*)(wsb + (57ull<<20));   // [N,128] bf16
  bf16u* P1  = (bf16u*)(wsb + (58ull<<20));   // [N,96]  bf16 (dt|at|ma)
  bf16u* P2  = (bf16u*)(wsb + (58ull<<20) + (768ull<<10)); // [N,32] bf16

  // 1. mix -> S4
  k_prep<<<4096, 256, 0, stream>>>(x, tmx, MIX);
  // 2. lo = tanh(mix @ maa_w1^T)
  k_gemm_mfma<true,-1><<<dim3(1,32),256,0,stream>>>(MIX, maa_w1, maa_w1, maa_w1,
                                                    128, 128, LO, 128, CC, 128);
  // 3. xm[g]: X0->S5, X1->S6, X2->S4(over MIX), X3->S0
  k_gemm_nn<32,1,-1><<<dim3(8,32),256,0,stream>>>(LO + 0*32, 128, maa_w2 + (size_t)0*32*CC, X0, x, tmaa + (size_t)0*CC);
  k_gemm_nn<32,1,-1><<<dim3(8,32),256,0,stream>>>(LO + 1*32, 128, maa_w2 + (size_t)1*32*CC, X1, x, tmaa + (size_t)1*CC);
  k_gemm_nn<32,1,-1><<<dim3(8,32),256,0,stream>>>(LO + 2*32, 128, maa_w2 + (size_t)2*32*CC, X2, x, tmaa + (size_t)2*CC);
  k_gemm_nn<32,1,-1><<<dim3(8,32),256,0,stream>>>(LO + 3*32, 128, maa_w2 + (size_t)3*32*CC, X3, x, tmaa + (size_t)3*CC);
  // 4. P1 <- X1 (then X1/S6 free)
  k_gemm_mfma<true,-1><<<dim3(1,32),256,0,stream>>>(X1, decay_w1, aaa_w1, ma_w1,
                                                    64, 80, P1, 96, CC, 64);
  // 5. V <- X3*Wv -> S6 (then X3/S0 free)
  k_gemm_mfma<true,-1><<<dim3(8,32),256,0,stream>>>(X3, Wv, Wv, Wv, CC, CC, V, CC, CC, 0);
  // 6. P2 <- X2
  k_gemm_mfma<true,-1><<<dim3(1,32),256,0,stream>>>(X2, kkk_w1, mk_w1, mk_w1,
                                                    16, 32, P2, 32, CC, 16);
  // 7. GT <- X0
  k_gemm_mfma<true,-1><<<dim3(1,32),256,0,stream>>>(X0, gate_w1, gate_w1, gate_w1,
                                                    128, 128, GT, 128, CC, 128);
  // 8. raw k0 = X2*Wk -> KPACK kf-pos (POFF=128)
  k_gemm_mfma<true,128><<<dim3(8,32),256,0,stream>>>(X2, Wk, Wk, Wk, CC, CC, KP, CC, CC, 0);
  // 9. raw w2a = P1[:, :64] @ decay_w2 -> KPACK u-pos (POFF=192)
  k_gemm_nn<64,0,192><<<dim3(8,32),256,0,stream>>>(P1, 96, decay_w2, KP, nullptr, nullptr);
  // 10. R <- X0*Wr -> S4 (X2 dead)
  k_gemm_mfma<true,-1><<<dim3(8,32),256,0,stream>>>(X0, Wr, Wr, Wr, CC, CC, R, CC, CC, 0);
  // 11. fused elementwise in-place on KPACK
  k_elem<<<1024, 256, 0, stream>>>(KP, P1, P2,
                                   kkk_w2, aaa_w2, ma_w2, mk_w2,
                                   t_decay, t_aaaaa, t_misc_a, t_misc_k);
  // 12. recurrence -> YT (S5; X0 dead after step 10)
  k_rec<<<256, 256, 0, stream>>>(R, KP, V, YT);
  // 13. groupnorm + bonus + gate -> YG in-place over R
  k_post<<<1024, 256, 0, stream>>>(YT, R, KP, V, GT, gate_w2, ln_w, ln_b, t_faaaa);
  // 14. out = yg @ Wo^T -> f32
  k_gemm_mfma<false,-1><<<dim3(8,32),256,0,stream>>>(R, Wo, Wo, Wo, CC, CC, d_out, CC, CC, 0);
}